// Round 1
// baseline (12068.047 us; speedup 1.0000x reference)
//
#include <hip/hip_runtime.h>
#include <math.h>

// ---------------------------------------------------------------------------
// Associator forward, fp32 baseline.
// Layouts: all activations are [C][Ncols] row-major matrices.
//   trk cols: 16384 (track*16 + t), det cols: 4096 (b*1024 + m), tr cols: 1024 (b*256 + n)
// Workspace need: ~93.4 MB (23,341,068 floats).
// ---------------------------------------------------------------------------

#define NCT 16384
#define NCD 4096
#define NCR 1024
#define ZROW 257
#define ZCOL 1025
#define ZBAT (ZROW*ZCOL)   // 263425

#define NORM_C  (-7.1546153569f)   // -log(1280)
#define LOG_NS  (6.9314718056f)    // log(1024)
#define LOG_MS  (5.5451774445f)    // log(256)
#define LOG_TOT (7.1546153569f)    // +log(1280)

// ---------------- generic GEMM: out = W @ [X0;X1] + bias (+res) (relu?) ----
// W [O][C] row-major. X rows [0,C0) from X0, [C0,C) from X1. out [O][N].
// O%128==0, N%128==0, C%8==0, C0%8==0.
__global__ __launch_bounds__(256) void gemm_kernel(
    const float* __restrict__ W, const float* __restrict__ X0,
    const float* __restrict__ X1, const float* __restrict__ bias,
    const float* __restrict__ res, float* __restrict__ out,
    int O, int C, int C0, int N, int relu)
{
    __shared__ float Ws[8][132];
    __shared__ float Xs[8][132];
    const int tid = threadIdx.x;
    const int n0 = blockIdx.x * 128, m0 = blockIdx.y * 128;
    const int tx = tid & 15, ty = tid >> 4;
    const int wr = tid >> 1, wk = (tid & 1) << 2;
    const int xr = tid >> 5, xc = (tid & 31) << 2;
    float acc[8][8] = {};
    for (int kb = 0; kb < C; kb += 8) {
        const float4 wv = *(const float4*)&W[(size_t)(m0 + wr) * C + kb + wk];
        const int krow = kb + xr;
        const float* Xsrc = (krow < C0) ? (X0 + (size_t)krow * N)
                                        : (X1 + (size_t)(krow - C0) * N);
        const float4 xv = *(const float4*)&Xsrc[n0 + xc];
        __syncthreads();
        Ws[wk+0][wr] = wv.x; Ws[wk+1][wr] = wv.y;
        Ws[wk+2][wr] = wv.z; Ws[wk+3][wr] = wv.w;
        *(float4*)&Xs[xr][xc] = xv;
        __syncthreads();
        #pragma unroll
        for (int kk = 0; kk < 8; ++kk) {
            float a[8], bv[8];
            #pragma unroll
            for (int i = 0; i < 4; ++i) { a[i]   = Ws[kk][ty*4 + i];
                                          a[4+i] = Ws[kk][64 + ty*4 + i]; }
            #pragma unroll
            for (int j = 0; j < 4; ++j) { bv[j]   = Xs[kk][tx*4 + j];
                                          bv[4+j] = Xs[kk][64 + tx*4 + j]; }
            #pragma unroll
            for (int i = 0; i < 8; ++i)
                #pragma unroll
                for (int j = 0; j < 8; ++j)
                    acc[i][j] = fmaf(a[i], bv[j], acc[i][j]);
        }
    }
    #pragma unroll
    for (int hi = 0; hi < 2; ++hi)
    #pragma unroll
    for (int io = 0; io < 4; ++io) {
        const int o = m0 + hi*64 + ty*4 + io;
        const float bs = bias[o];
        #pragma unroll
        for (int hj = 0; hj < 2; ++hj) {
            const int n = n0 + hj*64 + tx*4;
            float vals[4];
            #pragma unroll
            for (int j = 0; j < 4; ++j) {
                float v = acc[hi*4+io][hj*4+j] + bs;
                if (res) v += res[(size_t)o*N + n + j];
                if (relu) v = fmaxf(v, 0.f);
                vals[j] = v;
            }
            *(float4*)&out[(size_t)o*N + n] =
                make_float4(vals[0], vals[1], vals[2], vals[3]);
        }
    }
}

// ---------------- positional encoding ------------------------------------
__global__ void pe_kernel(const float* __restrict__ src, float* __restrict__ pe,
                          int N, int shift, int cstride)
{
    const int col = blockIdx.x * 256 + threadIdx.x;
    if (col >= N) return;
    const int seg = 1 << shift;
    const float pos = src[(size_t)(col >> shift) * cstride + (col & (seg - 1))];
    #pragma unroll 4
    for (int i = 0; i < 128; ++i) {
        const float div = expf((float)i * -0.07195578415606394f); // -ln(10000)/128
        const float ang = pos * div;
        pe[(size_t)(2*i) * N + col]   = sinf(ang);
        pe[(size_t)(2*i+1) * N + col] = cosf(ang);
    }
}

// ---------------- input repack (drop channel 0) ---------------------------
__global__ void repack_kernel(const float* __restrict__ src, float* __restrict__ dst,
                              int N, int shift, int cstride)
{
    const int col = blockIdx.x * 256 + threadIdx.x;
    const int c = blockIdx.y;
    if (col >= N) return;
    const int seg = 1 << shift;
    dst[(size_t)c * N + col] =
        src[(size_t)(col >> shift) * cstride + (size_t)(c + 1) * seg + (col & (seg - 1))];
}

// ---------------- fuser self-attention over time (n=m=16 per track) -------
__global__ __launch_bounds__(256) void fuser_attn_kernel(
    const float* __restrict__ Qb, const float* __restrict__ Kb,
    const float* __restrict__ Vb, float* __restrict__ Ob)
{
    __shared__ float qs[256][17], ks[256][17], vs[256][17];
    __shared__ float ps[4][16][17];
    const int trk = blockIdx.x, tid = threadIdx.x;
    const int col0 = trk * 16;
    for (int idx = tid; idx < 1024; idx += 256) {
        const int r = idx >> 2, seg = (idx & 3) << 2;
        const float4 q = *(const float4*)&Qb[(size_t)r * NCT + col0 + seg];
        const float4 k = *(const float4*)&Kb[(size_t)r * NCT + col0 + seg];
        const float4 v = *(const float4*)&Vb[(size_t)r * NCT + col0 + seg];
        qs[r][seg]=q.x; qs[r][seg+1]=q.y; qs[r][seg+2]=q.z; qs[r][seg+3]=q.w;
        ks[r][seg]=k.x; ks[r][seg+1]=k.y; ks[r][seg+2]=k.z; ks[r][seg+3]=k.w;
        vs[r][seg]=v.x; vs[r][seg+1]=v.y; vs[r][seg+2]=v.z; vs[r][seg+3]=v.w;
    }
    __syncthreads();
    {   // scores: thread group g=tid>>2 -> (h,n); 4 threads cover m in 4s
        const int g = tid >> 2, h = g >> 4, n = g & 15, mb = (tid & 3) << 2;
        float s[4] = {};
        #pragma unroll 4
        for (int hd = 0; hd < 64; ++hd) {
            const int c = hd*4 + h;
            const float q = qs[c][n];
            #pragma unroll
            for (int j = 0; j < 4; ++j) s[j] = fmaf(q, ks[c][mb + j], s[j]);
        }
        #pragma unroll
        for (int j = 0; j < 4; ++j) ps[h][n][mb + j] = s[j] * 0.125f;
    }
    __syncthreads();
    if (tid < 64) {
        const int hh = tid >> 4, nn = tid & 15;
        float mx = -INFINITY;
        for (int m = 0; m < 16; ++m) mx = fmaxf(mx, ps[hh][nn][m]);
        float sum = 0.f;
        for (int m = 0; m < 16; ++m) { const float p = expf(ps[hh][nn][m] - mx);
                                       ps[hh][nn][m] = p; sum += p; }
        const float inv = 1.f / sum;
        for (int m = 0; m < 16; ++m) ps[hh][nn][m] *= inv;
    }
    __syncthreads();
    {   // message: thread = channel c
        const int c = tid, hc = c & 3;
        float msg[16];
        #pragma unroll
        for (int n = 0; n < 16; ++n) {
            float a = 0.f;
            #pragma unroll
            for (int m = 0; m < 16; ++m) a = fmaf(ps[hc][n][m], vs[c][m], a);
            msg[n] = a;
        }
        __syncthreads();      // everyone done reading qs from scores phase
        #pragma unroll
        for (int n = 0; n < 16; ++n) qs[c][n] = msg[n];
    }
    __syncthreads();
    for (int idx = tid; idx < 1024; idx += 256) {
        const int r = idx >> 2, seg = (idx & 3) << 2;
        *(float4*)&Ob[(size_t)r * NCT + col0 + seg] =
            make_float4(qs[r][seg], qs[r][seg+1], qs[r][seg+2], qs[r][seg+3]);
    }
}

// ---------------- GNN attention, flash-style online softmax ---------------
// grid: (nq/64, H=4, B=4). Channels are hd*4+h. S tile overlays K tile LDS.
__global__ __launch_bounds__(256) void attn_kernel(
    const float* __restrict__ Qb, const float* __restrict__ Kb,
    const float* __restrict__ Vb, float* __restrict__ Ob,
    int nq, int nk, int NQ, int NK)
{
    __shared__ float Qs[64][65];
    __shared__ float KsS[64][65];   // K tile, later overwritten by S/P
    __shared__ float Vs[64][65];
    __shared__ float rmax[64], rsum[64], ralpha[64];
    const int b = blockIdx.z, h = blockIdx.y, nt = blockIdx.x;
    const int tid = threadIdx.x;
    const int qcol = b * nq + nt * 64;
    for (int idx = tid; idx < 1024; idx += 256) {
        const int hd = idx >> 4, seg = (idx & 15) << 2;
        const float4 q = *(const float4*)&Qb[(size_t)(hd*4 + h) * NQ + qcol + seg];
        Qs[hd][seg]=q.x; Qs[hd][seg+1]=q.y; Qs[hd][seg+2]=q.z; Qs[hd][seg+3]=q.w;
    }
    if (tid < 64) { rmax[tid] = -INFINITY; rsum[tid] = 0.f; }
    float acc[4][4] = {};               // [hd][n]
    const int thd = (tid & 15) * 4, tn = (tid >> 4) * 4;
    const int mtiles = nk >> 6;
    for (int mt = 0; mt < mtiles; ++mt) {
        const int kcol = b * nk + mt * 64;
        __syncthreads();                // prior readers of KsS/Vs done
        for (int idx = tid; idx < 1024; idx += 256) {
            const int hd = idx >> 4, seg = (idx & 15) << 2;
            const float4 k4 = *(const float4*)&Kb[(size_t)(hd*4 + h) * NK + kcol + seg];
            KsS[hd][seg]=k4.x; KsS[hd][seg+1]=k4.y; KsS[hd][seg+2]=k4.z; KsS[hd][seg+3]=k4.w;
            const float4 v4 = *(const float4*)&Vb[(size_t)(hd*4 + h) * NK + kcol + seg];
            Vs[hd][seg]=v4.x; Vs[hd][seg+1]=v4.y; Vs[hd][seg+2]=v4.z; Vs[hd][seg+3]=v4.w;
        }
        __syncthreads();
        float s[4][4] = {};             // n = tn+i, m = thd-slot reuse: tsm
        const int tsm = (tid & 15) * 4, tsn = (tid >> 4) * 4;
        #pragma unroll 4
        for (int hd = 0; hd < 64; ++hd) {
            float qv[4], kv[4];
            #pragma unroll
            for (int i = 0; i < 4; ++i) { qv[i] = Qs[hd][tsn + i]; kv[i] = KsS[hd][tsm + i]; }
            #pragma unroll
            for (int i = 0; i < 4; ++i)
                #pragma unroll
                for (int j = 0; j < 4; ++j) s[i][j] = fmaf(qv[i], kv[j], s[i][j]);
        }
        __syncthreads();                // all threads done reading K
        #pragma unroll
        for (int i = 0; i < 4; ++i)
            #pragma unroll
            for (int j = 0; j < 4; ++j) KsS[tsn + i][tsm + j] = s[i][j] * 0.125f;
        __syncthreads();
        if (tid < 64) {                 // per-row online softmax update
            const float mo = rmax[tid];
            float mx = mo;
            for (int m = 0; m < 64; ++m) mx = fmaxf(mx, KsS[tid][m]);
            const float al = expf(mo - mx);       // first tile: exp(-inf)=0
            float sum = 0.f;
            for (int m = 0; m < 64; ++m) { const float p = expf(KsS[tid][m] - mx);
                                           KsS[tid][m] = p; sum += p; }
            rsum[tid] = rsum[tid] * al + sum;
            rmax[tid] = mx; ralpha[tid] = al;
        }
        __syncthreads();
        float alj[4];
        #pragma unroll
        for (int j = 0; j < 4; ++j) alj[j] = ralpha[tn + j];
        #pragma unroll
        for (int i = 0; i < 4; ++i)
            #pragma unroll
            for (int j = 0; j < 4; ++j) acc[i][j] *= alj[j];
        for (int m = 0; m < 64; ++m) {
            float vv[4], pp[4];
            #pragma unroll
            for (int i = 0; i < 4; ++i) vv[i] = Vs[thd + i][m];
            #pragma unroll
            for (int j = 0; j < 4; ++j) pp[j] = KsS[tn + j][m];
            #pragma unroll
            for (int i = 0; i < 4; ++i)
                #pragma unroll
                for (int j = 0; j < 4; ++j) acc[i][j] = fmaf(vv[i], pp[j], acc[i][j]);
        }
    }
    __syncthreads();
    float rs[4];
    #pragma unroll
    for (int j = 0; j < 4; ++j) rs[j] = 1.f / rsum[tn + j];
    #pragma unroll
    for (int i = 0; i < 4; ++i)
        #pragma unroll
        for (int j = 0; j < 4; ++j)
            Ob[(size_t)((thd + i) * 4 + h) * NQ + qcol + tn + j] = acc[i][j] * rs[j];
}

// ---------------- mean pool over time -------------------------------------
__global__ void meanpool_kernel(const float* __restrict__ x, float* __restrict__ tr)
{
    const int trk = blockIdx.x * 256 + threadIdx.x;
    const int d = blockIdx.y;
    const float* p = x + (size_t)d * NCT + (size_t)trk * 16;
    float s = 0.f;
    #pragma unroll
    for (int t = 0; t < 16; ++t) s += p[t];
    tr[(size_t)d * NCR + trk] = s * 0.0625f;
}

// ---------------- scores = m0^T m1 / 16 into Z0 ---------------------------
__global__ __launch_bounds__(256) void scores_kernel(
    const float* __restrict__ m0, const float* __restrict__ m1, float* __restrict__ Z0)
{
    __shared__ float As[8][68];
    __shared__ float Bs[8][68];
    const int bm = blockIdx.x, bn = blockIdx.y, b = blockIdx.z;
    const int tid = threadIdx.x;
    const int n0 = bn * 64, mm0 = bm * 64;
    const int tx = tid & 15, ty = tid >> 4;
    float acc[4][4] = {};
    for (int kb = 0; kb < 256; kb += 8) {
        __syncthreads();
        for (int idx = tid; idx < 512; idx += 256) {
            const int r = idx >> 6, cc = idx & 63;
            As[r][cc] = m0[(size_t)(kb + r) * NCR + b * 256 + n0 + cc];
            Bs[r][cc] = m1[(size_t)(kb + r) * NCD + b * 1024 + mm0 + cc];
        }
        __syncthreads();
        #pragma unroll
        for (int kk = 0; kk < 8; ++kk) {
            float a[4], bv[4];
            #pragma unroll
            for (int i = 0; i < 4; ++i) { a[i] = As[kk][ty*4 + i]; bv[i] = Bs[kk][tx*4 + i]; }
            #pragma unroll
            for (int i = 0; i < 4; ++i)
                #pragma unroll
                for (int j = 0; j < 4; ++j) acc[i][j] = fmaf(a[i], bv[j], acc[i][j]);
        }
    }
    #pragma unroll
    for (int i = 0; i < 4; ++i)
        #pragma unroll
        for (int j = 0; j < 4; ++j)
            Z0[(size_t)b * ZBAT + (size_t)(n0 + ty*4 + i) * ZCOL + mm0 + tx*4 + j] =
                acc[i][j] * 0.0625f;
}

// ---------------- sinkhorn ------------------------------------------------
__global__ void sink_init_kernel(float* __restrict__ Z0, float* __restrict__ v,
                                 const float* __restrict__ binp)
{
    const float alpha = binp[0];
    const int idx = blockIdx.x * 256 + threadIdx.x;
    if (idx < 4 * ZCOL) v[idx] = 0.f;
    if (idx < 4 * 1281) {
        const int b = idx / 1281, e = idx % 1281;
        if (e < 1025) Z0[(size_t)b * ZBAT + 256 * ZCOL + e] = alpha;
        else          Z0[(size_t)b * ZBAT + (size_t)(e - 1025) * ZCOL + 1024] = alpha;
    }
}

__global__ __launch_bounds__(256) void sink_u_kernel(
    const float* __restrict__ Z0, const float* __restrict__ v, float* __restrict__ u)
{
    const int w = threadIdx.x >> 6, lane = threadIdx.x & 63;
    const int row = blockIdx.x * 4 + w;          // 0..1027
    const int b = row / 257, i = row % 257;
    const float* z  = Z0 + (size_t)b * ZBAT + (size_t)i * ZCOL;
    const float* vb = v + b * ZCOL;
    float zz[17];
    float mx = -INFINITY;
    #pragma unroll
    for (int k = 0; k < 16; ++k) {
        zz[k] = z[lane + k*64] + vb[lane + k*64];
        mx = fmaxf(mx, zz[k]);
    }
    zz[16] = (lane == 0) ? (z[1024] + vb[1024]) : -INFINITY;
    mx = fmaxf(mx, zz[16]);
    #pragma unroll
    for (int off = 32; off; off >>= 1) mx = fmaxf(mx, __shfl_xor(mx, off));
    float s = 0.f;
    #pragma unroll
    for (int k = 0; k < 17; ++k) s += expf(zz[k] - mx);
    #pragma unroll
    for (int off = 32; off; off >>= 1) s += __shfl_xor(s, off);
    if (lane == 0) {
        const float lmu = (i < 256) ? NORM_C : (LOG_NS + NORM_C);
        u[b * 257 + i] = lmu - (mx + logf(s));
    }
}

__global__ __launch_bounds__(1024) void sink_v_kernel(
    const float* __restrict__ Z0, const float* __restrict__ u, float* __restrict__ v)
{
    __shared__ float red[16][64];
    const int tile = blockIdx.x, b = blockIdx.y;
    const int lane = threadIdx.x & 63, w = threadIdx.x >> 6;
    const int j = tile * 64 + lane;
    const bool jv = (j < ZCOL);
    const float* zb = Z0 + (size_t)b * ZBAT;
    const float* ub = u + b * 257;
    float zz[17];
    float mx = -INFINITY;
    #pragma unroll
    for (int k = 0; k < 17; ++k) {
        const int i = w + 16 * k;
        float val = -INFINITY;
        if (jv && i < 257) val = zb[(size_t)i * ZCOL + j] + ub[i];
        zz[k] = val; mx = fmaxf(mx, val);
    }
    red[w][lane] = mx;
    __syncthreads();
    float M = -INFINITY;
    #pragma unroll
    for (int ww = 0; ww < 16; ++ww) M = fmaxf(M, red[ww][lane]);
    __syncthreads();
    float s = 0.f;
    if (jv) {
        #pragma unroll
        for (int k = 0; k < 17; ++k) s += expf(zz[k] - M);
    }
    red[w][lane] = s;
    __syncthreads();
    if (w == 0 && jv) {
        float S = 0.f;
        #pragma unroll
        for (int ww = 0; ww < 16; ++ww) S += red[ww][lane];
        const float lnu = (j < 1024) ? NORM_C : (LOG_MS + NORM_C);
        v[b * ZCOL + j] = lnu - (M + logf(S));
    }
}

__global__ void sink_out_kernel(const float* __restrict__ Z0, const float* __restrict__ u,
                                const float* __restrict__ v, float* __restrict__ out)
{
    const int j = blockIdx.x * 256 + threadIdx.x;
    const int i = blockIdx.y, b = blockIdx.z;
    if (j < ZCOL) {
        const size_t idx = (size_t)b * ZBAT + (size_t)i * ZCOL + j;
        out[idx] = Z0[idx] + u[b * 257 + i] + v[b * ZCOL + j] + LOG_TOT;
    }
}

// ---------------------------------------------------------------------------
static inline void gemm(hipStream_t st, const float* W, const float* X0,
                        const float* X1, int C0, const float* bias,
                        const float* res, float* out, int O, int C, int N, int relu)
{
    dim3 g(N / 128, O / 128);
    gemm_kernel<<<g, 256, 0, st>>>(W, X0, X1, bias, res, out, O, C, C0, N, relu);
}

extern "C" void kernel_launch(void* const* d_in, const int* in_sizes, int n_in,
                              void* d_out, int out_size, void* d_ws, size_t ws_size,
                              hipStream_t stream)
{
    (void)in_sizes; (void)n_in; (void)out_size; (void)ws_size;
    const float* det_in = (const float*)d_in[0];
    const float* trk_in = (const float*)d_in[1];
    const float* enc_w1 = (const float*)d_in[2];
    const float* enc_b1 = (const float*)d_in[3];
    const float* enc_w2 = (const float*)d_in[4];
    const float* enc_b2 = (const float*)d_in[5];
    const float* fus_pw = (const float*)d_in[6];
    const float* fus_pb = (const float*)d_in[7];
    const float* fus_mw = (const float*)d_in[8];
    const float* fus_mb = (const float*)d_in[9];
    const float* fus_m1w = (const float*)d_in[10];
    const float* fus_m1b = (const float*)d_in[11];
    const float* fus_m2w = (const float*)d_in[12];
    const float* fus_m2b = (const float*)d_in[13];
    const float* gnn_pw = (const float*)d_in[14];
    const float* gnn_pb = (const float*)d_in[15];
    const float* gnn_mw = (const float*)d_in[16];
    const float* gnn_mb = (const float*)d_in[17];
    const float* gnn_m1w = (const float*)d_in[18];
    const float* gnn_m1b = (const float*)d_in[19];
    const float* gnn_m2w = (const float*)d_in[20];
    const float* gnn_m2b = (const float*)d_in[21];
    const float* final_w = (const float*)d_in[22];
    const float* final_b = (const float*)d_in[23];
    const float* bin_sc  = (const float*)d_in[24];
    float* out = (float*)d_out;

    float* ws = (float*)d_ws;
    float* XF  = ws;                       // 4,194,304  fuser state x
    float* R   = ws + 4194304;             // 16,777,216 temp region
    float* DET = ws + 20971520;            // 1,048,576
    float* TR  = ws + 22020096;            //   262,144
    float* Z0  = ws + 22282240;            // 1,053,700
    float* U   = ws + 23335940;            //     1,028
    float* V   = ws + 23336968;            //     4,100
    // region aliases (fuser): Q,K,V contiguous so qkv is one O=768 GEMM
    float* Qf = R;
    float* Kf = R + 4194304;
    float* Vf = R + 8388608;
    float* MS = R + 12582912;
    // region aliases (GNN): QT/KT/VT and QD/KD/VD contiguous
    float* QT = R;            float* KT = R + 262144;  float* VT = R + 524288;
    float* QD = R + 786432;   float* KD = R + 1835008; float* VD = R + 2883584;
    float* MSG0 = R + 3932160; float* MSG1 = R + 4194304;
    float* M0 = R + 5242880;   float* M1 = R + 5505024;
    // H0 overlays KT..VT (512x1024), H1 overlays KD..VD (512x4096)

    // ================= encoder (tracks) + fuser ===========================
    pe_kernel<<<NCT/256, 256, 0, stream>>>(trk_in, MS, NCT, 4, 257*16);
    repack_kernel<<<dim3(NCT/256, 256), 256, 0, stream>>>(trk_in, Qf, NCT, 4, 257*16);
    gemm(stream, enc_w1, Qf, Qf, 256, enc_b1, nullptr, Kf, 256, 256, NCT, 1);
    gemm(stream, enc_w2, Kf, Kf, 256, enc_b2, MS, XF, 256, 256, NCT, 0);

    for (int l = 0; l < 4; ++l) {
        gemm(stream, fus_pw + l*196608, XF, XF, 256, fus_pb + l*768,
             nullptr, Qf, 768, 256, NCT, 0);
        fuser_attn_kernel<<<1024, 256, 0, stream>>>(Qf, Kf, Vf, MS);
        gemm(stream, fus_mw + l*65536, MS, MS, 256, fus_mb + l*256,
             nullptr, Qf, 256, 256, NCT, 0);                       // M -> Qf
        gemm(stream, fus_m1w + l*262144, XF, Qf, 256, fus_m1b + l*512,
             nullptr, Kf, 512, 512, NCT, 1);                       // H -> Kf..Vf
        gemm(stream, fus_m2w + l*131072, Kf, Kf, 512, fus_m2b + l*256,
             XF, XF, 256, 512, NCT, 0);                            // x += ...
    }
    meanpool_kernel<<<dim3(NCR/256, 256), 256, 0, stream>>>(XF, TR);

    // ================= encoder (detections) ===============================
    pe_kernel<<<NCD/256, 256, 0, stream>>>(det_in, MS, NCD, 10, 257*1024);
    repack_kernel<<<dim3(NCD/256, 256), 256, 0, stream>>>(det_in, Qf, NCD, 10, 257*1024);
    gemm(stream, enc_w1, Qf, Qf, 256, enc_b1, nullptr, Kf, 256, 256, NCD, 1);
    gemm(stream, enc_w2, Kf, Kf, 256, enc_b2, MS, DET, 256, 256, NCD, 0);

    // ================= GNN ================================================
    for (int l = 0; l < 12; ++l) {
        const float* pw  = gnn_pw + l*196608;
        const float* pb  = gnn_pb + l*768;
        const float* mw  = gnn_mw + l*65536;
        const float* mb  = gnn_mb + l*256;
        const float* m1w = gnn_m1w + l*262144;
        const float* m1b = gnn_m1b + l*512;
        const float* m2w = gnn_m2w + l*131072;
        const float* m2b = gnn_m2b + l*256;
        const bool cross = (l & 1);

        gemm(stream, pw, TR, TR, 256, pb, nullptr, QT, 768, 256, NCR, 0);
        gemm(stream, pw, DET, DET, 256, pb, nullptr, QD, 768, 256, NCD, 0);

        attn_kernel<<<dim3(4, 4, 4), 256, 0, stream>>>(
            QT, cross ? KD : KT, cross ? VD : VT, MSG0,
            256, cross ? 1024 : 256, NCR, cross ? NCD : NCR);
        attn_kernel<<<dim3(16, 4, 4), 256, 0, stream>>>(
            QD, cross ? KT : KD, cross ? VT : VD, MSG1,
            1024, cross ? 256 : 1024, NCD, cross ? NCR : NCD);

        gemm(stream, mw, MSG0, MSG0, 256, mb, nullptr, M0, 256, 256, NCR, 0);
        gemm(stream, mw, MSG1, MSG1, 256, mb, nullptr, M1, 256, 256, NCD, 0);
        gemm(stream, m1w, TR, M0, 256, m1b, nullptr, KT, 512, 512, NCR, 1);   // H0
        gemm(stream, m1w, DET, M1, 256, m1b, nullptr, KD, 512, 512, NCD, 1);  // H1
        gemm(stream, m2w, KT, KT, 512, m2b, TR, TR, 256, 512, NCR, 0);
        gemm(stream, m2w, KD, KD, 512, m2b, DET, DET, 256, 512, NCD, 0);
    }

    // ================= final projections + scores + sinkhorn ==============
    gemm(stream, final_w, TR, TR, 256, final_b, nullptr, QT, 256, 256, NCR, 0);
    gemm(stream, final_w, DET, DET, 256, final_b, nullptr, QD, 256, 256, NCD, 0);
    scores_kernel<<<dim3(16, 4, 4), 256, 0, stream>>>(QT, QD, Z0);
    sink_init_kernel<<<21, 256, 0, stream>>>(Z0, V, bin_sc);
    for (int it = 0; it < 100; ++it) {
        sink_u_kernel<<<257, 256, 0, stream>>>(Z0, V, U);
        sink_v_kernel<<<dim3(17, 4), 1024, 0, stream>>>(Z0, U, V);
    }
    sink_out_kernel<<<dim3(5, 257, 4), 256, 0, stream>>>(Z0, U, V, out);
}

// Round 2
// 6991.722 us; speedup vs baseline: 1.7260x; 1.7260x over previous
//
#include <hip/hip_runtime.h>
#include <math.h>

// ---------------------------------------------------------------------------
// Associator forward. GEMMs: split-fp16 (hi+lo) MFMA, fp32 accumulate.
// Layouts: all activations are [C][Ncols] row-major fp32 matrices.
//   trk cols: 16384 (track*16 + t), det cols: 4096 (b*1024 + m), tr cols: 1024 (b*256 + n)
// ---------------------------------------------------------------------------

#define NCT 16384
#define NCD 4096
#define NCR 1024
#define ZROW 257
#define ZCOL 1025
#define ZBAT (ZROW*ZCOL)   // 263425

#define NORM_C  (-7.1546153569f)   // -log(1280)
#define LOG_NS  (6.9314718056f)    // log(1024)
#define LOG_MS  (5.5451774445f)    // log(256)
#define LOG_TOT (7.1546153569f)    // +log(1280)

typedef _Float16 f16x8 __attribute__((ext_vector_type(8)));
typedef _Float16 f16x4 __attribute__((ext_vector_type(4)));
typedef float f32x4 __attribute__((ext_vector_type(4)));

#define APAD 40   // LDS row stride in halves (80 B: 16B-aligned rows)

// ---------------- GEMM: out = W @ [X0;X1] + bias (+res) (relu?) -----------
// W [O][C] fp32. X rows [0,C0) from X0, [C0,C) from X1. out [O][N] fp32.
// O%128==0, N%128==0, C%32==0, C0%32==0.
// Split-fp16: x = hi + lo; acc += Ah*Bh + Ah*Bl + Al*Bh  (fp32-grade inputs).
__global__ __launch_bounds__(256) void gemm_kernel(
    const float* __restrict__ W, const float* __restrict__ X0,
    const float* __restrict__ X1, const float* __restrict__ bias,
    const float* __restrict__ res, float* __restrict__ out,
    int O, int C, int C0, int N, int relu)
{
    __shared__ _Float16 Ah[128][APAD], Al[128][APAD];
    __shared__ _Float16 Bh[128][APAD], Bl[128][APAD];
    const int tid = threadIdx.x;
    const int n0 = blockIdx.x * 128, m0 = blockIdx.y * 128;
    const int wave = tid >> 6, lane = tid & 63;
    const int wo = (wave >> 1) * 64, wn = (wave & 1) * 64;
    const int lm = lane & 15, lq = lane >> 4;
    const int ar = tid >> 1, akh = (tid & 1) << 4;   // A stage: row, k-half
    const int bkg = tid & 7, bng = tid >> 3;         // B stage: k-grp, n-grp

    f32x4 acc[4][4] = {};

    for (int kb = 0; kb < C; kb += 32) {
        // ---- global loads (fp32) ----
        float4 av[4];
        const float* wp = W + (size_t)(m0 + ar) * C + kb + akh;
        #pragma unroll
        for (int q = 0; q < 4; ++q) av[q] = *(const float4*)(wp + 4 * q);
        float4 xv[4];
        #pragma unroll
        for (int r = 0; r < 4; ++r) {
            const int krow = kb + bkg * 4 + r;
            const float* xs = (krow < C0) ? X0 + (size_t)krow * N
                                          : X1 + (size_t)(krow - C0) * N;
            xv[r] = *(const float4*)(xs + n0 + bng * 4);
        }
        __syncthreads();   // prior iteration's fragment reads complete
        // ---- A: convert + store (row-major, k contiguous) ----
        {
            _Float16 hbuf[16], lbuf[16];
            #pragma unroll
            for (int q = 0; q < 4; ++q) {
                const float* f = (const float*)&av[q];
                #pragma unroll
                for (int c = 0; c < 4; ++c) {
                    const float x = f[c];
                    const _Float16 h = (_Float16)x;
                    hbuf[q * 4 + c] = h;
                    lbuf[q * 4 + c] = (_Float16)(x - (float)h);
                }
            }
            *(f16x8*)&Ah[ar][akh]     = *(const f16x8*)&hbuf[0];
            *(f16x8*)&Ah[ar][akh + 8] = *(const f16x8*)&hbuf[8];
            *(f16x8*)&Al[ar][akh]     = *(const f16x8*)&lbuf[0];
            *(f16x8*)&Al[ar][akh + 8] = *(const f16x8*)&lbuf[8];
        }
        // ---- B: convert + transposed store (Bs[n][k], k contiguous) ----
        #pragma unroll
        for (int j = 0; j < 4; ++j) {
            _Float16 hb[4], lb[4];
            #pragma unroll
            for (int r = 0; r < 4; ++r) {
                const float x = ((const float*)&xv[r])[j];
                const _Float16 h = (_Float16)x;
                hb[r] = h;
                lb[r] = (_Float16)(x - (float)h);
            }
            *(f16x4*)&Bh[bng * 4 + j][bkg * 4] = *(const f16x4*)&hb[0];
            *(f16x4*)&Bl[bng * 4 + j][bkg * 4] = *(const f16x4*)&lb[0];
        }
        __syncthreads();
        // ---- fragments + MFMA ----
        f16x8 bh[4], bl[4];
        #pragma unroll
        for (int t = 0; t < 4; ++t) {
            bh[t] = *(const f16x8*)&Bh[wn + t * 16 + lm][lq * 8];
            bl[t] = *(const f16x8*)&Bl[wn + t * 16 + lm][lq * 8];
        }
        #pragma unroll
        for (int mt = 0; mt < 4; ++mt) {
            const f16x8 ah = *(const f16x8*)&Ah[wo + mt * 16 + lm][lq * 8];
            const f16x8 al = *(const f16x8*)&Al[wo + mt * 16 + lm][lq * 8];
            #pragma unroll
            for (int nt = 0; nt < 4; ++nt) {
                acc[mt][nt] = __builtin_amdgcn_mfma_f32_16x16x32_f16(ah, bh[nt], acc[mt][nt], 0, 0, 0);
                acc[mt][nt] = __builtin_amdgcn_mfma_f32_16x16x32_f16(ah, bl[nt], acc[mt][nt], 0, 0, 0);
                acc[mt][nt] = __builtin_amdgcn_mfma_f32_16x16x32_f16(al, bh[nt], acc[mt][nt], 0, 0, 0);
            }
        }
    }
    // ---- epilogue: C/D layout col=lane&15, row=quad*4+reg ----
    #pragma unroll
    for (int mt = 0; mt < 4; ++mt) {
        #pragma unroll
        for (int rg = 0; rg < 4; ++rg) {
            const int o = m0 + wo + mt * 16 + lq * 4 + rg;
            const float bs = bias[o];
            const size_t rowoff = (size_t)o * N + n0 + wn;
            #pragma unroll
            for (int nt = 0; nt < 4; ++nt) {
                float v = acc[mt][nt][rg] + bs;
                const size_t idx = rowoff + nt * 16 + lm;
                if (res) v += res[idx];
                if (relu) v = fmaxf(v, 0.f);
                out[idx] = v;
            }
        }
    }
}

// ---------------- positional encoding ------------------------------------
__global__ void pe_kernel(const float* __restrict__ src, float* __restrict__ pe,
                          int N, int shift, int cstride)
{
    const int col = blockIdx.x * 256 + threadIdx.x;
    if (col >= N) return;
    const int seg = 1 << shift;
    const float pos = src[(size_t)(col >> shift) * cstride + (col & (seg - 1))];
    #pragma unroll 4
    for (int i = 0; i < 128; ++i) {
        const float div = expf((float)i * -0.07195578415606394f); // -ln(10000)/128
        const float ang = pos * div;
        pe[(size_t)(2*i) * N + col]   = sinf(ang);
        pe[(size_t)(2*i+1) * N + col] = cosf(ang);
    }
}

// ---------------- input repack (drop channel 0) ---------------------------
__global__ void repack_kernel(const float* __restrict__ src, float* __restrict__ dst,
                              int N, int shift, int cstride)
{
    const int col = blockIdx.x * 256 + threadIdx.x;
    const int c = blockIdx.y;
    if (col >= N) return;
    const int seg = 1 << shift;
    dst[(size_t)c * N + col] =
        src[(size_t)(col >> shift) * cstride + (size_t)(c + 1) * seg + (col & (seg - 1))];
}

// ---------------- fuser self-attention over time (n=m=16 per track) -------
__global__ __launch_bounds__(256) void fuser_attn_kernel(
    const float* __restrict__ Qb, const float* __restrict__ Kb,
    const float* __restrict__ Vb, float* __restrict__ Ob)
{
    __shared__ float qs[256][17], ks[256][17], vs[256][17];
    __shared__ float ps[4][16][17];
    const int trk = blockIdx.x, tid = threadIdx.x;
    const int col0 = trk * 16;
    for (int idx = tid; idx < 1024; idx += 256) {
        const int r = idx >> 2, seg = (idx & 3) << 2;
        const float4 q = *(const float4*)&Qb[(size_t)r * NCT + col0 + seg];
        const float4 k = *(const float4*)&Kb[(size_t)r * NCT + col0 + seg];
        const float4 v = *(const float4*)&Vb[(size_t)r * NCT + col0 + seg];
        qs[r][seg]=q.x; qs[r][seg+1]=q.y; qs[r][seg+2]=q.z; qs[r][seg+3]=q.w;
        ks[r][seg]=k.x; ks[r][seg+1]=k.y; ks[r][seg+2]=k.z; ks[r][seg+3]=k.w;
        vs[r][seg]=v.x; vs[r][seg+1]=v.y; vs[r][seg+2]=v.z; vs[r][seg+3]=v.w;
    }
    __syncthreads();
    {   // scores: thread group g=tid>>2 -> (h,n); 4 threads cover m in 4s
        const int g = tid >> 2, h = g >> 4, n = g & 15, mb = (tid & 3) << 2;
        float s[4] = {};
        #pragma unroll 4
        for (int hd = 0; hd < 64; ++hd) {
            const int c = hd*4 + h;
            const float q = qs[c][n];
            #pragma unroll
            for (int j = 0; j < 4; ++j) s[j] = fmaf(q, ks[c][mb + j], s[j]);
        }
        #pragma unroll
        for (int j = 0; j < 4; ++j) ps[h][n][mb + j] = s[j] * 0.125f;
    }
    __syncthreads();
    if (tid < 64) {
        const int hh = tid >> 4, nn = tid & 15;
        float mx = -INFINITY;
        for (int m = 0; m < 16; ++m) mx = fmaxf(mx, ps[hh][nn][m]);
        float sum = 0.f;
        for (int m = 0; m < 16; ++m) { const float p = expf(ps[hh][nn][m] - mx);
                                       ps[hh][nn][m] = p; sum += p; }
        const float inv = 1.f / sum;
        for (int m = 0; m < 16; ++m) ps[hh][nn][m] *= inv;
    }
    __syncthreads();
    {   // message: thread = channel c
        const int c = tid, hc = c & 3;
        float msg[16];
        #pragma unroll
        for (int n = 0; n < 16; ++n) {
            float a = 0.f;
            #pragma unroll
            for (int m = 0; m < 16; ++m) a = fmaf(ps[hc][n][m], vs[c][m], a);
            msg[n] = a;
        }
        __syncthreads();      // everyone done reading qs from scores phase
        #pragma unroll
        for (int n = 0; n < 16; ++n) qs[c][n] = msg[n];
    }
    __syncthreads();
    for (int idx = tid; idx < 1024; idx += 256) {
        const int r = idx >> 2, seg = (idx & 3) << 2;
        *(float4*)&Ob[(size_t)r * NCT + col0 + seg] =
            make_float4(qs[r][seg], qs[r][seg+1], qs[r][seg+2], qs[r][seg+3]);
    }
}

// ---------------- GNN attention, flash-style online softmax ---------------
// grid: (nq/64, H=4, B=4). Channels are hd*4+h. S tile overlays K tile LDS.
__global__ __launch_bounds__(256) void attn_kernel(
    const float* __restrict__ Qb, const float* __restrict__ Kb,
    const float* __restrict__ Vb, float* __restrict__ Ob,
    int nq, int nk, int NQ, int NK)
{
    __shared__ float Qs[64][65];
    __shared__ float KsS[64][65];   // K tile, later overwritten by S/P
    __shared__ float Vs[64][65];
    __shared__ float rmax[64], rsum[64], ralpha[64];
    const int b = blockIdx.z, h = blockIdx.y, nt = blockIdx.x;
    const int tid = threadIdx.x;
    const int qcol = b * nq + nt * 64;
    for (int idx = tid; idx < 1024; idx += 256) {
        const int hd = idx >> 4, seg = (idx & 15) << 2;
        const float4 q = *(const float4*)&Qb[(size_t)(hd*4 + h) * NQ + qcol + seg];
        Qs[hd][seg]=q.x; Qs[hd][seg+1]=q.y; Qs[hd][seg+2]=q.z; Qs[hd][seg+3]=q.w;
    }
    if (tid < 64) { rmax[tid] = -INFINITY; rsum[tid] = 0.f; }
    float acc[4][4] = {};               // [hd][n]
    const int thd = (tid & 15) * 4, tn = (tid >> 4) * 4;
    const int mtiles = nk >> 6;
    for (int mt = 0; mt < mtiles; ++mt) {
        const int kcol = b * nk + mt * 64;
        __syncthreads();                // prior readers of KsS/Vs done
        for (int idx = tid; idx < 1024; idx += 256) {
            const int hd = idx >> 4, seg = (idx & 15) << 2;
            const float4 k4 = *(const float4*)&Kb[(size_t)(hd*4 + h) * NK + kcol + seg];
            KsS[hd][seg]=k4.x; KsS[hd][seg+1]=k4.y; KsS[hd][seg+2]=k4.z; KsS[hd][seg+3]=k4.w;
            const float4 v4 = *(const float4*)&Vb[(size_t)(hd*4 + h) * NK + kcol + seg];
            Vs[hd][seg]=v4.x; Vs[hd][seg+1]=v4.y; Vs[hd][seg+2]=v4.z; Vs[hd][seg+3]=v4.w;
        }
        __syncthreads();
        float s[4][4] = {};             // n = tn+i, m = thd-slot reuse: tsm
        const int tsm = (tid & 15) * 4, tsn = (tid >> 4) * 4;
        #pragma unroll 4
        for (int hd = 0; hd < 64; ++hd) {
            float qv[4], kv[4];
            #pragma unroll
            for (int i = 0; i < 4; ++i) { qv[i] = Qs[hd][tsn + i]; kv[i] = KsS[hd][tsm + i]; }
            #pragma unroll
            for (int i = 0; i < 4; ++i)
                #pragma unroll
                for (int j = 0; j < 4; ++j) s[i][j] = fmaf(qv[i], kv[j], s[i][j]);
        }
        __syncthreads();                // all threads done reading K
        #pragma unroll
        for (int i = 0; i < 4; ++i)
            #pragma unroll
            for (int j = 0; j < 4; ++j) KsS[tsn + i][tsm + j] = s[i][j] * 0.125f;
        __syncthreads();
        if (tid < 64) {                 // per-row online softmax update
            const float mo = rmax[tid];
            float mx = mo;
            for (int m = 0; m < 64; ++m) mx = fmaxf(mx, KsS[tid][m]);
            const float al = expf(mo - mx);       // first tile: exp(-inf)=0
            float sum = 0.f;
            for (int m = 0; m < 64; ++m) { const float p = expf(KsS[tid][m] - mx);
                                           KsS[tid][m] = p; sum += p; }
            rsum[tid] = rsum[tid] * al + sum;
            rmax[tid] = mx; ralpha[tid] = al;
        }
        __syncthreads();
        float alj[4];
        #pragma unroll
        for (int j = 0; j < 4; ++j) alj[j] = ralpha[tn + j];
        #pragma unroll
        for (int i = 0; i < 4; ++i)
            #pragma unroll
            for (int j = 0; j < 4; ++j) acc[i][j] *= alj[j];
        for (int m = 0; m < 64; ++m) {
            float vv[4], pp[4];
            #pragma unroll
            for (int i = 0; i < 4; ++i) vv[i] = Vs[thd + i][m];
            #pragma unroll
            for (int j = 0; j < 4; ++j) pp[j] = KsS[tn + j][m];
            #pragma unroll
            for (int i = 0; i < 4; ++i)
                #pragma unroll
                for (int j = 0; j < 4; ++j) acc[i][j] = fmaf(vv[i], pp[j], acc[i][j]);
        }
    }
    __syncthreads();
    float rs[4];
    #pragma unroll
    for (int j = 0; j < 4; ++j) rs[j] = 1.f / rsum[tn + j];
    #pragma unroll
    for (int i = 0; i < 4; ++i)
        #pragma unroll
        for (int j = 0; j < 4; ++j)
            Ob[(size_t)((thd + i) * 4 + h) * NQ + qcol + tn + j] = acc[i][j] * rs[j];
}

// ---------------- mean pool over time -------------------------------------
__global__ void meanpool_kernel(const float* __restrict__ x, float* __restrict__ tr)
{
    const int trk = blockIdx.x * 256 + threadIdx.x;
    const int d = blockIdx.y;
    const float* p = x + (size_t)d * NCT + (size_t)trk * 16;
    float s = 0.f;
    #pragma unroll
    for (int t = 0; t < 16; ++t) s += p[t];
    tr[(size_t)d * NCR + trk] = s * 0.0625f;
}

// ---------------- scores = m0^T m1 / 16 into Z0 ---------------------------
__global__ __launch_bounds__(256) void scores_kernel(
    const float* __restrict__ m0, const float* __restrict__ m1, float* __restrict__ Z0)
{
    __shared__ float As[8][68];
    __shared__ float Bs[8][68];
    const int bm = blockIdx.x, bn = blockIdx.y, b = blockIdx.z;
    const int tid = threadIdx.x;
    const int n0 = bn * 64, mm0 = bm * 64;
    const int tx = tid & 15, ty = tid >> 4;
    float acc[4][4] = {};
    for (int kb = 0; kb < 256; kb += 8) {
        __syncthreads();
        for (int idx = tid; idx < 512; idx += 256) {
            const int r = idx >> 6, cc = idx & 63;
            As[r][cc] = m0[(size_t)(kb + r) * NCR + b * 256 + n0 + cc];
            Bs[r][cc] = m1[(size_t)(kb + r) * NCD + b * 1024 + mm0 + cc];
        }
        __syncthreads();
        #pragma unroll
        for (int kk = 0; kk < 8; ++kk) {
            float a[4], bv[4];
            #pragma unroll
            for (int i = 0; i < 4; ++i) { a[i] = As[kk][ty*4 + i]; bv[i] = Bs[kk][tx*4 + i]; }
            #pragma unroll
            for (int i = 0; i < 4; ++i)
                #pragma unroll
                for (int j = 0; j < 4; ++j) acc[i][j] = fmaf(a[i], bv[j], acc[i][j]);
        }
    }
    #pragma unroll
    for (int i = 0; i < 4; ++i)
        #pragma unroll
        for (int j = 0; j < 4; ++j)
            Z0[(size_t)b * ZBAT + (size_t)(n0 + ty*4 + i) * ZCOL + mm0 + tx*4 + j] =
                acc[i][j] * 0.0625f;
}

// ---------------- sinkhorn ------------------------------------------------
__global__ void sink_init_kernel(float* __restrict__ Z0, float* __restrict__ v,
                                 const float* __restrict__ binp)
{
    const float alpha = binp[0];
    const int idx = blockIdx.x * 256 + threadIdx.x;
    if (idx < 4 * ZCOL) v[idx] = 0.f;
    if (idx < 4 * 1281) {
        const int b = idx / 1281, e = idx % 1281;
        if (e < 1025) Z0[(size_t)b * ZBAT + 256 * ZCOL + e] = alpha;
        else          Z0[(size_t)b * ZBAT + (size_t)(e - 1025) * ZCOL + 1024] = alpha;
    }
}

__global__ __launch_bounds__(256) void sink_u_kernel(
    const float* __restrict__ Z0, const float* __restrict__ v, float* __restrict__ u)
{
    const int w = threadIdx.x >> 6, lane = threadIdx.x & 63;
    const int row = blockIdx.x * 4 + w;          // 0..1027
    const int b = row / 257, i = row % 257;
    const float* z  = Z0 + (size_t)b * ZBAT + (size_t)i * ZCOL;
    const float* vb = v + b * ZCOL;
    float zz[17];
    float mx = -INFINITY;
    #pragma unroll
    for (int k = 0; k < 16; ++k) {
        zz[k] = z[lane + k*64] + vb[lane + k*64];
        mx = fmaxf(mx, zz[k]);
    }
    zz[16] = (lane == 0) ? (z[1024] + vb[1024]) : -INFINITY;
    mx = fmaxf(mx, zz[16]);
    #pragma unroll
    for (int off = 32; off; off >>= 1) mx = fmaxf(mx, __shfl_xor(mx, off));
    float s = 0.f;
    #pragma unroll
    for (int k = 0; k < 17; ++k) s += expf(zz[k] - mx);
    #pragma unroll
    for (int off = 32; off; off >>= 1) s += __shfl_xor(s, off);
    if (lane == 0) {
        const float lmu = (i < 256) ? NORM_C : (LOG_NS + NORM_C);
        u[b * 257 + i] = lmu - (mx + logf(s));
    }
}

__global__ __launch_bounds__(1024) void sink_v_kernel(
    const float* __restrict__ Z0, const float* __restrict__ u, float* __restrict__ v)
{
    __shared__ float red[16][64];
    const int tile = blockIdx.x, b = blockIdx.y;
    const int lane = threadIdx.x & 63, w = threadIdx.x >> 6;
    const int j = tile * 64 + lane;
    const bool jv = (j < ZCOL);
    const float* zb = Z0 + (size_t)b * ZBAT;
    const float* ub = u + b * 257;
    float zz[17];
    float mx = -INFINITY;
    #pragma unroll
    for (int k = 0; k < 17; ++k) {
        const int i = w + 16 * k;
        float val = -INFINITY;
        if (jv && i < 257) val = zb[(size_t)i * ZCOL + j] + ub[i];
        zz[k] = val; mx = fmaxf(mx, val);
    }
    red[w][lane] = mx;
    __syncthreads();
    float M = -INFINITY;
    #pragma unroll
    for (int ww = 0; ww < 16; ++ww) M = fmaxf(M, red[ww][lane]);
    __syncthreads();
    float s = 0.f;
    if (jv) {
        #pragma unroll
        for (int k = 0; k < 17; ++k) s += expf(zz[k] - M);
    }
    red[w][lane] = s;
    __syncthreads();
    if (w == 0 && jv) {
        float S = 0.f;
        #pragma unroll
        for (int ww = 0; ww < 16; ++ww) S += red[ww][lane];
        const float lnu = (j < 1024) ? NORM_C : (LOG_MS + NORM_C);
        v[b * ZCOL + j] = lnu - (M + logf(S));
    }
}

__global__ void sink_out_kernel(const float* __restrict__ Z0, const float* __restrict__ u,
                                const float* __restrict__ v, float* __restrict__ out)
{
    const int j = blockIdx.x * 256 + threadIdx.x;
    const int i = blockIdx.y, b = blockIdx.z;
    if (j < ZCOL) {
        const size_t idx = (size_t)b * ZBAT + (size_t)i * ZCOL + j;
        out[idx] = Z0[idx] + u[b * 257 + i] + v[b * ZCOL + j] + LOG_TOT;
    }
}

// ---------------------------------------------------------------------------
static inline void gemm(hipStream_t st, const float* W, const float* X0,
                        const float* X1, int C0, const float* bias,
                        const float* res, float* out, int O, int C, int N, int relu)
{
    dim3 g(N / 128, O / 128);
    gemm_kernel<<<g, 256, 0, st>>>(W, X0, X1, bias, res, out, O, C, C0, N, relu);
}

extern "C" void kernel_launch(void* const* d_in, const int* in_sizes, int n_in,
                              void* d_out, int out_size, void* d_ws, size_t ws_size,
                              hipStream_t stream)
{
    (void)in_sizes; (void)n_in; (void)out_size; (void)ws_size;
    const float* det_in = (const float*)d_in[0];
    const float* trk_in = (const float*)d_in[1];
    const float* enc_w1 = (const float*)d_in[2];
    const float* enc_b1 = (const float*)d_in[3];
    const float* enc_w2 = (const float*)d_in[4];
    const float* enc_b2 = (const float*)d_in[5];
    const float* fus_pw = (const float*)d_in[6];
    const float* fus_pb = (const float*)d_in[7];
    const float* fus_mw = (const float*)d_in[8];
    const float* fus_mb = (const float*)d_in[9];
    const float* fus_m1w = (const float*)d_in[10];
    const float* fus_m1b = (const float*)d_in[11];
    const float* fus_m2w = (const float*)d_in[12];
    const float* fus_m2b = (const float*)d_in[13];
    const float* gnn_pw = (const float*)d_in[14];
    const float* gnn_pb = (const float*)d_in[15];
    const float* gnn_mw = (const float*)d_in[16];
    const float* gnn_mb = (const float*)d_in[17];
    const float* gnn_m1w = (const float*)d_in[18];
    const float* gnn_m1b = (const float*)d_in[19];
    const float* gnn_m2w = (const float*)d_in[20];
    const float* gnn_m2b = (const float*)d_in[21];
    const float* final_w = (const float*)d_in[22];
    const float* final_b = (const float*)d_in[23];
    const float* bin_sc  = (const float*)d_in[24];
    float* out = (float*)d_out;

    float* ws = (float*)d_ws;
    float* XF  = ws;                       // 4,194,304  fuser state x
    float* R   = ws + 4194304;             // 16,777,216 temp region
    float* DET = ws + 20971520;            // 1,048,576
    float* TR  = ws + 22020096;            //   262,144
    float* Z0  = ws + 22282240;            // 1,053,700
    float* U   = ws + 23335940;            //     1,028
    float* V   = ws + 23336968;            //     4,100
    // region aliases (fuser): Q,K,V contiguous so qkv is one O=768 GEMM
    float* Qf = R;
    float* Kf = R + 4194304;
    float* Vf = R + 8388608;
    float* MS = R + 12582912;
    // region aliases (GNN): QT/KT/VT and QD/KD/VD contiguous
    float* QT = R;            float* KT = R + 262144;  float* VT = R + 524288;
    float* QD = R + 786432;   float* KD = R + 1835008; float* VD = R + 2883584;
    float* MSG0 = R + 3932160; float* MSG1 = R + 4194304;
    float* M0 = R + 5242880;   float* M1 = R + 5505024;
    // H0 overlays KT..VT (512x1024), H1 overlays KD..VD (512x4096)

    // ================= encoder (tracks) + fuser ===========================
    pe_kernel<<<NCT/256, 256, 0, stream>>>(trk_in, MS, NCT, 4, 257*16);
    repack_kernel<<<dim3(NCT/256, 256), 256, 0, stream>>>(trk_in, Qf, NCT, 4, 257*16);
    gemm(stream, enc_w1, Qf, Qf, 256, enc_b1, nullptr, Kf, 256, 256, NCT, 1);
    gemm(stream, enc_w2, Kf, Kf, 256, enc_b2, MS, XF, 256, 256, NCT, 0);

    for (int l = 0; l < 4; ++l) {
        gemm(stream, fus_pw + l*196608, XF, XF, 256, fus_pb + l*768,
             nullptr, Qf, 768, 256, NCT, 0);
        fuser_attn_kernel<<<1024, 256, 0, stream>>>(Qf, Kf, Vf, MS);
        gemm(stream, fus_mw + l*65536, MS, MS, 256, fus_mb + l*256,
             nullptr, Qf, 256, 256, NCT, 0);                       // M -> Qf
        gemm(stream, fus_m1w + l*262144, XF, Qf, 256, fus_m1b + l*512,
             nullptr, Kf, 512, 512, NCT, 1);                       // H -> Kf..Vf
        gemm(stream, fus_m2w + l*131072, Kf, Kf, 512, fus_m2b + l*256,
             XF, XF, 256, 512, NCT, 0);                            // x += ...
    }
    meanpool_kernel<<<dim3(NCR/256, 256), 256, 0, stream>>>(XF, TR);

    // ================= encoder (detections) ===============================
    pe_kernel<<<NCD/256, 256, 0, stream>>>(det_in, MS, NCD, 10, 257*1024);
    repack_kernel<<<dim3(NCD/256, 256), 256, 0, stream>>>(det_in, Qf, NCD, 10, 257*1024);
    gemm(stream, enc_w1, Qf, Qf, 256, enc_b1, nullptr, Kf, 256, 256, NCD, 1);
    gemm(stream, enc_w2, Kf, Kf, 256, enc_b2, MS, DET, 256, 256, NCD, 0);

    // ================= GNN ================================================
    for (int l = 0; l < 12; ++l) {
        const float* pw  = gnn_pw + l*196608;
        const float* pb  = gnn_pb + l*768;
        const float* mw  = gnn_mw + l*65536;
        const float* mb  = gnn_mb + l*256;
        const float* m1w = gnn_m1w + l*262144;
        const float* m1b = gnn_m1b + l*512;
        const float* m2w = gnn_m2w + l*131072;
        const float* m2b = gnn_m2b + l*256;
        const bool cross = (l & 1);

        gemm(stream, pw, TR, TR, 256, pb, nullptr, QT, 768, 256, NCR, 0);
        gemm(stream, pw, DET, DET, 256, pb, nullptr, QD, 768, 256, NCD, 0);

        attn_kernel<<<dim3(4, 4, 4), 256, 0, stream>>>(
            QT, cross ? KD : KT, cross ? VD : VT, MSG0,
            256, cross ? 1024 : 256, NCR, cross ? NCD : NCR);
        attn_kernel<<<dim3(16, 4, 4), 256, 0, stream>>>(
            QD, cross ? KT : KD, cross ? VT : VD, MSG1,
            1024, cross ? 256 : 1024, NCD, cross ? NCR : NCD);

        gemm(stream, mw, MSG0, MSG0, 256, mb, nullptr, M0, 256, 256, NCR, 0);
        gemm(stream, mw, MSG1, MSG1, 256, mb, nullptr, M1, 256, 256, NCD, 0);
        gemm(stream, m1w, TR, M0, 256, m1b, nullptr, KT, 512, 512, NCR, 1);   // H0
        gemm(stream, m1w, DET, M1, 256, m1b, nullptr, KD, 512, 512, NCD, 1);  // H1
        gemm(stream, m2w, KT, KT, 512, m2b, TR, TR, 256, 512, NCR, 0);
        gemm(stream, m2w, KD, KD, 512, m2b, DET, DET, 256, 512, NCD, 0);
    }

    // ================= final projections + scores + sinkhorn ==============
    gemm(stream, final_w, TR, TR, 256, final_b, nullptr, QT, 256, 256, NCR, 0);
    gemm(stream, final_w, DET, DET, 256, final_b, nullptr, QD, 256, 256, NCD, 0);
    scores_kernel<<<dim3(16, 4, 4), 256, 0, stream>>>(QT, QD, Z0);
    sink_init_kernel<<<21, 256, 0, stream>>>(Z0, V, bin_sc);
    for (int it = 0; it < 100; ++it) {
        sink_u_kernel<<<257, 256, 0, stream>>>(Z0, V, U);
        sink_v_kernel<<<dim3(17, 4), 1024, 0, stream>>>(Z0, U, V);
    }
    sink_out_kernel<<<dim3(5, 257, 4), 256, 0, stream>>>(Z0, U, V, out);
}

// Round 3
// 5952.873 us; speedup vs baseline: 2.0273x; 1.1745x over previous
//
#include <hip/hip_runtime.h>
#include <math.h>

// ---------------------------------------------------------------------------
// Associator forward. GEMMs: split-fp16 (hi+lo) MFMA, fp32 accumulate.
// Layouts: activations are [C][Ncols] row-major fp32.
//   trk cols: 16384 (track*16+t); GNN combined cols: 5120 = [tr: b*256+n | 1024 + det: b*1024+m]
// ---------------------------------------------------------------------------

#define NCT 16384
#define NCD 4096
#define NCB 5120
#define ZROW 257
#define ZCOL 1025
#define ZBAT (ZROW*ZCOL)   // 263425

#define NORM_C  (-7.1546153569f)   // -log(1280)
#define LOG_NS  (6.9314718056f)    // log(1024)
#define LOG_MS  (5.5451774445f)    // log(256)
#define LOG_TOT (7.1546153569f)    // +log(1280)

typedef _Float16 f16x8 __attribute__((ext_vector_type(8)));
typedef _Float16 f16x4 __attribute__((ext_vector_type(4)));
typedef float f32x4 __attribute__((ext_vector_type(4)));

#define APAD 40   // LDS row stride in halves (80 B: 16B-aligned rows)

// ---------------- GEMM: out = W @ [X0;X1] + bias (+res) (relu?) -----------
// W [O][C] fp32. X rows [0,C0) from X0, [C0,C) from X1 (both stride N).
// out stride No, res stride Nr. O%128==0, N%128==0, C%32==0, C0%32==0.
// Split-fp16: x = hi + lo; acc += Ah*Bh + Ah*Bl + Al*Bh  (fp32-grade inputs).
__global__ __launch_bounds__(256) void gemm_kernel(
    const float* __restrict__ W, const float* __restrict__ X0,
    const float* __restrict__ X1, const float* __restrict__ bias,
    const float* __restrict__ res, float* __restrict__ out,
    int O, int C, int C0, int N, int Nr, int No, int relu)
{
    __shared__ _Float16 Ah[128][APAD], Al[128][APAD];
    __shared__ _Float16 Bh[128][APAD], Bl[128][APAD];
    const int tid = threadIdx.x;
    const int n0 = blockIdx.x * 128, m0 = blockIdx.y * 128;
    const int wave = tid >> 6, lane = tid & 63;
    const int wo = (wave >> 1) * 64, wn = (wave & 1) * 64;
    const int lm = lane & 15, lq = lane >> 4;
    const int ar = tid >> 1, akh = (tid & 1) << 4;   // A stage: row, k-half
    const int bkg = tid & 7, bng = tid >> 3;         // B stage: k-grp, n-grp

    f32x4 acc[4][4] = {};

    for (int kb = 0; kb < C; kb += 32) {
        // ---- global loads (fp32) ----
        float4 av[4];
        const float* wp = W + (size_t)(m0 + ar) * C + kb + akh;
        #pragma unroll
        for (int q = 0; q < 4; ++q) av[q] = *(const float4*)(wp + 4 * q);
        float4 xv[4];
        #pragma unroll
        for (int r = 0; r < 4; ++r) {
            const int krow = kb + bkg * 4 + r;
            const float* xs = (krow < C0) ? X0 + (size_t)krow * N
                                          : X1 + (size_t)(krow - C0) * N;
            xv[r] = *(const float4*)(xs + n0 + bng * 4);
        }
        __syncthreads();   // prior iteration's fragment reads complete
        // ---- A: convert + store (row-major, k contiguous) ----
        {
            _Float16 hbuf[16], lbuf[16];
            #pragma unroll
            for (int q = 0; q < 4; ++q) {
                const float* f = (const float*)&av[q];
                #pragma unroll
                for (int c = 0; c < 4; ++c) {
                    const float x = f[c];
                    const _Float16 h = (_Float16)x;
                    hbuf[q * 4 + c] = h;
                    lbuf[q * 4 + c] = (_Float16)(x - (float)h);
                }
            }
            *(f16x8*)&Ah[ar][akh]     = *(const f16x8*)&hbuf[0];
            *(f16x8*)&Ah[ar][akh + 8] = *(const f16x8*)&hbuf[8];
            *(f16x8*)&Al[ar][akh]     = *(const f16x8*)&lbuf[0];
            *(f16x8*)&Al[ar][akh + 8] = *(const f16x8*)&lbuf[8];
        }
        // ---- B: convert + transposed store (Bs[n][k], k contiguous) ----
        #pragma unroll
        for (int j = 0; j < 4; ++j) {
            _Float16 hb[4], lb[4];
            #pragma unroll
            for (int r = 0; r < 4; ++r) {
                const float x = ((const float*)&xv[r])[j];
                const _Float16 h = (_Float16)x;
                hb[r] = h;
                lb[r] = (_Float16)(x - (float)h);
            }
            *(f16x4*)&Bh[bng * 4 + j][bkg * 4] = *(const f16x4*)&hb[0];
            *(f16x4*)&Bl[bng * 4 + j][bkg * 4] = *(const f16x4*)&lb[0];
        }
        __syncthreads();
        // ---- fragments + MFMA ----
        f16x8 bh[4], bl[4];
        #pragma unroll
        for (int t = 0; t < 4; ++t) {
            bh[t] = *(const f16x8*)&Bh[wn + t * 16 + lm][lq * 8];
            bl[t] = *(const f16x8*)&Bl[wn + t * 16 + lm][lq * 8];
        }
        #pragma unroll
        for (int mt = 0; mt < 4; ++mt) {
            const f16x8 ah = *(const f16x8*)&Ah[wo + mt * 16 + lm][lq * 8];
            const f16x8 al = *(const f16x8*)&Al[wo + mt * 16 + lm][lq * 8];
            #pragma unroll
            for (int nt = 0; nt < 4; ++nt) {
                acc[mt][nt] = __builtin_amdgcn_mfma_f32_16x16x32_f16(ah, bh[nt], acc[mt][nt], 0, 0, 0);
                acc[mt][nt] = __builtin_amdgcn_mfma_f32_16x16x32_f16(ah, bl[nt], acc[mt][nt], 0, 0, 0);
                acc[mt][nt] = __builtin_amdgcn_mfma_f32_16x16x32_f16(al, bh[nt], acc[mt][nt], 0, 0, 0);
            }
        }
    }
    // ---- epilogue: C/D layout col=lane&15, row=quad*4+reg ----
    #pragma unroll
    for (int mt = 0; mt < 4; ++mt) {
        #pragma unroll
        for (int rg = 0; rg < 4; ++rg) {
            const int o = m0 + wo + mt * 16 + lq * 4 + rg;
            const float bs = bias[o];
            #pragma unroll
            for (int nt = 0; nt < 4; ++nt) {
                const int n = n0 + wn + nt * 16 + lm;
                float v = acc[mt][nt][rg] + bs;
                if (res) v += res[(size_t)o * Nr + n];
                if (relu) v = fmaxf(v, 0.f);
                out[(size_t)o * No + n] = v;
            }
        }
    }
}

// ---------------- positional encoding ------------------------------------
__global__ void pe_kernel(const float* __restrict__ src, float* __restrict__ pe,
                          int N, int shift, int cstride)
{
    const int col = blockIdx.x * 256 + threadIdx.x;
    if (col >= N) return;
    const int seg = 1 << shift;
    const float pos = src[(size_t)(col >> shift) * cstride + (col & (seg - 1))];
    #pragma unroll 4
    for (int i = 0; i < 128; ++i) {
        const float div = expf((float)i * -0.07195578415606394f); // -ln(10000)/128
        const float ang = pos * div;
        pe[(size_t)(2*i) * N + col]   = sinf(ang);
        pe[(size_t)(2*i+1) * N + col] = cosf(ang);
    }
}

// ---------------- input repack (drop channel 0) ---------------------------
__global__ void repack_kernel(const float* __restrict__ src, float* __restrict__ dst,
                              int N, int shift, int cstride)
{
    const int col = blockIdx.x * 256 + threadIdx.x;
    const int c = blockIdx.y;
    if (col >= N) return;
    const int seg = 1 << shift;
    dst[(size_t)c * N + col] =
        src[(size_t)(col >> shift) * cstride + (size_t)(c + 1) * seg + (col & (seg - 1))];
}

// ---------------- fuser self-attention over time (n=m=16 per track) -------
__global__ __launch_bounds__(256) void fuser_attn_kernel(
    const float* __restrict__ Qb, const float* __restrict__ Kb,
    const float* __restrict__ Vb, float* __restrict__ Ob)
{
    __shared__ float qs[256][17], ks[256][17], vs[256][17];
    __shared__ float ps[4][16][17];
    const int trk = blockIdx.x, tid = threadIdx.x;
    const int col0 = trk * 16;
    for (int idx = tid; idx < 1024; idx += 256) {
        const int r = idx >> 2, seg = (idx & 3) << 2;
        const float4 q = *(const float4*)&Qb[(size_t)r * NCT + col0 + seg];
        const float4 k = *(const float4*)&Kb[(size_t)r * NCT + col0 + seg];
        const float4 v = *(const float4*)&Vb[(size_t)r * NCT + col0 + seg];
        qs[r][seg]=q.x; qs[r][seg+1]=q.y; qs[r][seg+2]=q.z; qs[r][seg+3]=q.w;
        ks[r][seg]=k.x; ks[r][seg+1]=k.y; ks[r][seg+2]=k.z; ks[r][seg+3]=k.w;
        vs[r][seg]=v.x; vs[r][seg+1]=v.y; vs[r][seg+2]=v.z; vs[r][seg+3]=v.w;
    }
    __syncthreads();
    {   // scores: thread group g=tid>>2 -> (h,n); 4 threads cover m in 4s
        const int g = tid >> 2, h = g >> 4, n = g & 15, mb = (tid & 3) << 2;
        float s[4] = {};
        #pragma unroll 4
        for (int hd = 0; hd < 64; ++hd) {
            const int c = hd*4 + h;
            const float q = qs[c][n];
            #pragma unroll
            for (int j = 0; j < 4; ++j) s[j] = fmaf(q, ks[c][mb + j], s[j]);
        }
        #pragma unroll
        for (int j = 0; j < 4; ++j) ps[h][n][mb + j] = s[j] * 0.125f;
    }
    __syncthreads();
    if (tid < 64) {
        const int hh = tid >> 4, nn = tid & 15;
        float mx = -INFINITY;
        for (int m = 0; m < 16; ++m) mx = fmaxf(mx, ps[hh][nn][m]);
        float sum = 0.f;
        for (int m = 0; m < 16; ++m) { const float p = expf(ps[hh][nn][m] - mx);
                                       ps[hh][nn][m] = p; sum += p; }
        const float inv = 1.f / sum;
        for (int m = 0; m < 16; ++m) ps[hh][nn][m] *= inv;
    }
    __syncthreads();
    {   // message: thread = channel c
        const int c = tid, hc = c & 3;
        float msg[16];
        #pragma unroll
        for (int n = 0; n < 16; ++n) {
            float a = 0.f;
            #pragma unroll
            for (int m = 0; m < 16; ++m) a = fmaf(ps[hc][n][m], vs[c][m], a);
            msg[n] = a;
        }
        __syncthreads();      // everyone done reading qs from scores phase
        #pragma unroll
        for (int n = 0; n < 16; ++n) qs[c][n] = msg[n];
    }
    __syncthreads();
    for (int idx = tid; idx < 1024; idx += 256) {
        const int r = idx >> 2, seg = (idx & 3) << 2;
        *(float4*)&Ob[(size_t)r * NCT + col0 + seg] =
            make_float4(qs[r][seg], qs[r][seg+1], qs[r][seg+2], qs[r][seg+3]);
    }
}

// ---------------- GNN attention, flash-style online softmax ---------------
// grid: (nq/64, H=4, B=4). Channels are hd*4+h. S tile overlaid on K LDS.
__global__ __launch_bounds__(256) void attn_kernel(
    const float* __restrict__ Qb, const float* __restrict__ Kb,
    const float* __restrict__ Vb, float* __restrict__ Ob,
    int nq, int nk, int NQ, int NK)
{
    __shared__ float Qs[64][65];
    __shared__ float KsS[64][65];   // K tile, later overwritten by S/P
    __shared__ float Vs[64][65];
    __shared__ float rmax[64], rsum[64], ralpha[64];
    const int b = blockIdx.z, h = blockIdx.y, nt = blockIdx.x;
    const int tid = threadIdx.x;
    const int qcol = b * nq + nt * 64;
    for (int idx = tid; idx < 1024; idx += 256) {
        const int hd = idx >> 4, seg = (idx & 15) << 2;
        const float4 q = *(const float4*)&Qb[(size_t)(hd*4 + h) * NQ + qcol + seg];
        Qs[hd][seg]=q.x; Qs[hd][seg+1]=q.y; Qs[hd][seg+2]=q.z; Qs[hd][seg+3]=q.w;
    }
    if (tid < 64) { rmax[tid] = -INFINITY; rsum[tid] = 0.f; }
    float acc[4][4] = {};               // [hd][n]
    const int thd = (tid & 15) * 4, tn = (tid >> 4) * 4;
    const int mtiles = nk >> 6;
    for (int mt = 0; mt < mtiles; ++mt) {
        const int kcol = b * nk + mt * 64;
        __syncthreads();                // prior readers of KsS/Vs done
        for (int idx = tid; idx < 1024; idx += 256) {
            const int hd = idx >> 4, seg = (idx & 15) << 2;
            const float4 k4 = *(const float4*)&Kb[(size_t)(hd*4 + h) * NK + kcol + seg];
            KsS[hd][seg]=k4.x; KsS[hd][seg+1]=k4.y; KsS[hd][seg+2]=k4.z; KsS[hd][seg+3]=k4.w;
            const float4 v4 = *(const float4*)&Vb[(size_t)(hd*4 + h) * NK + kcol + seg];
            Vs[hd][seg]=v4.x; Vs[hd][seg+1]=v4.y; Vs[hd][seg+2]=v4.z; Vs[hd][seg+3]=v4.w;
        }
        __syncthreads();
        float s[4][4] = {};
        const int tsm = (tid & 15) * 4, tsn = (tid >> 4) * 4;
        #pragma unroll 4
        for (int hd = 0; hd < 64; ++hd) {
            float qv[4], kv[4];
            #pragma unroll
            for (int i = 0; i < 4; ++i) { qv[i] = Qs[hd][tsn + i]; kv[i] = KsS[hd][tsm + i]; }
            #pragma unroll
            for (int i = 0; i < 4; ++i)
                #pragma unroll
                for (int j = 0; j < 4; ++j) s[i][j] = fmaf(qv[i], kv[j], s[i][j]);
        }
        __syncthreads();                // all threads done reading K
        #pragma unroll
        for (int i = 0; i < 4; ++i)
            #pragma unroll
            for (int j = 0; j < 4; ++j) KsS[tsn + i][tsm + j] = s[i][j] * 0.125f;
        __syncthreads();
        if (tid < 64) {                 // per-row online softmax update
            const float mo = rmax[tid];
            float mx = mo;
            for (int m = 0; m < 64; ++m) mx = fmaxf(mx, KsS[tid][m]);
            const float al = expf(mo - mx);       // first tile: exp(-inf)=0
            float sum = 0.f;
            for (int m = 0; m < 64; ++m) { const float p = expf(KsS[tid][m] - mx);
                                           KsS[tid][m] = p; sum += p; }
            rsum[tid] = rsum[tid] * al + sum;
            rmax[tid] = mx; ralpha[tid] = al;
        }
        __syncthreads();
        float alj[4];
        #pragma unroll
        for (int j = 0; j < 4; ++j) alj[j] = ralpha[tn + j];
        #pragma unroll
        for (int i = 0; i < 4; ++i)
            #pragma unroll
            for (int j = 0; j < 4; ++j) acc[i][j] *= alj[j];
        for (int m = 0; m < 64; ++m) {
            float vv[4], pp[4];
            #pragma unroll
            for (int i = 0; i < 4; ++i) vv[i] = Vs[thd + i][m];
            #pragma unroll
            for (int j = 0; j < 4; ++j) pp[j] = KsS[tn + j][m];
            #pragma unroll
            for (int i = 0; i < 4; ++i)
                #pragma unroll
                for (int j = 0; j < 4; ++j) acc[i][j] = fmaf(vv[i], pp[j], acc[i][j]);
        }
    }
    __syncthreads();
    float rs[4];
    #pragma unroll
    for (int j = 0; j < 4; ++j) rs[j] = 1.f / rsum[tn + j];
    #pragma unroll
    for (int i = 0; i < 4; ++i)
        #pragma unroll
        for (int j = 0; j < 4; ++j)
            Ob[(size_t)((thd + i) * 4 + h) * NQ + qcol + tn + j] = acc[i][j] * rs[j];
}

// ---------------- mean pool over time (into combined cols [0,1024)) -------
__global__ void meanpool_kernel(const float* __restrict__ x, float* __restrict__ tr)
{
    const int trk = blockIdx.x * 256 + threadIdx.x;
    const int d = blockIdx.y;
    const float* p = x + (size_t)d * NCT + (size_t)trk * 16;
    float s = 0.f;
    #pragma unroll
    for (int t = 0; t < 16; ++t) s += p[t];
    tr[(size_t)d * NCB + trk] = s * 0.0625f;
}

// ---------------- scores = m0^T m1 / 16 into Z0 (from combined M) ---------
__global__ __launch_bounds__(256) void scores_kernel(
    const float* __restrict__ M, float* __restrict__ Z0)
{
    __shared__ float As[8][68];
    __shared__ float Bs[8][68];
    const int bm = blockIdx.x, bn = blockIdx.y, b = blockIdx.z;
    const int tid = threadIdx.x;
    const int n0 = bn * 64, mm0 = bm * 64;
    const int tx = tid & 15, ty = tid >> 4;
    float acc[4][4] = {};
    for (int kb = 0; kb < 256; kb += 8) {
        __syncthreads();
        for (int idx = tid; idx < 512; idx += 256) {
            const int r = idx >> 6, cc = idx & 63;
            As[r][cc] = M[(size_t)(kb + r) * NCB + b * 256 + n0 + cc];
            Bs[r][cc] = M[(size_t)(kb + r) * NCB + 1024 + b * 1024 + mm0 + cc];
        }
        __syncthreads();
        #pragma unroll
        for (int kk = 0; kk < 8; ++kk) {
            float a[4], bv[4];
            #pragma unroll
            for (int i = 0; i < 4; ++i) { a[i] = As[kk][ty*4 + i]; bv[i] = Bs[kk][tx*4 + i]; }
            #pragma unroll
            for (int i = 0; i < 4; ++i)
                #pragma unroll
                for (int j = 0; j < 4; ++j) acc[i][j] = fmaf(a[i], bv[j], acc[i][j]);
        }
    }
    #pragma unroll
    for (int i = 0; i < 4; ++i)
        #pragma unroll
        for (int j = 0; j < 4; ++j)
            Z0[(size_t)b * ZBAT + (size_t)(n0 + ty*4 + i) * ZCOL + mm0 + tx*4 + j] =
                acc[i][j] * 0.0625f;
}

// ---------------- sinkhorn ------------------------------------------------
__global__ void sink_init_kernel(float* __restrict__ Z0, float* __restrict__ v,
                                 const float* __restrict__ binp)
{
    const float alpha = binp[0];
    const int idx = blockIdx.x * 256 + threadIdx.x;
    if (idx < 4 * ZCOL) v[idx] = 0.f;
    if (idx < 4 * 1281) {
        const int b = idx / 1281, e = idx % 1281;
        if (e < 1025) Z0[(size_t)b * ZBAT + 256 * ZCOL + e] = alpha;
        else          Z0[(size_t)b * ZBAT + (size_t)(e - 1025) * ZCOL + 1024] = alpha;
    }
}

__global__ __launch_bounds__(256) void sink_u_kernel(
    const float* __restrict__ Z0, const float* __restrict__ v, float* __restrict__ u)
{
    const int w = threadIdx.x >> 6, lane = threadIdx.x & 63;
    const int row = blockIdx.x * 4 + w;          // 0..1027
    const int b = row / 257, i = row % 257;
    const float* z  = Z0 + (size_t)b * ZBAT + (size_t)i * ZCOL;
    const float* vb = v + b * ZCOL;
    float zz[17];
    float mx = -INFINITY;
    #pragma unroll
    for (int k = 0; k < 16; ++k) {
        zz[k] = z[lane + k*64] + vb[lane + k*64];
        mx = fmaxf(mx, zz[k]);
    }
    zz[16] = (lane == 0) ? (z[1024] + vb[1024]) : -INFINITY;
    mx = fmaxf(mx, zz[16]);
    #pragma unroll
    for (int off = 32; off; off >>= 1) mx = fmaxf(mx, __shfl_xor(mx, off));
    float s = 0.f;
    #pragma unroll
    for (int k = 0; k < 17; ++k) s += expf(zz[k] - mx);
    #pragma unroll
    for (int off = 32; off; off >>= 1) s += __shfl_xor(s, off);
    if (lane == 0) {
        const float lmu = (i < 256) ? NORM_C : (LOG_NS + NORM_C);
        u[b * 257 + i] = lmu - (mx + logf(s));
    }
}

__global__ __launch_bounds__(1024) void sink_v_kernel(
    const float* __restrict__ Z0, const float* __restrict__ u, float* __restrict__ v)
{
    __shared__ float red[16][64];
    const int tile = blockIdx.x, b = blockIdx.y;
    const int lane = threadIdx.x & 63, w = threadIdx.x >> 6;
    const int j = tile * 64 + lane;
    const bool jv = (j < ZCOL);
    const float* zb = Z0 + (size_t)b * ZBAT;
    const float* ub = u + b * 257;
    float zz[17];
    float mx = -INFINITY;
    #pragma unroll
    for (int k = 0; k < 17; ++k) {
        const int i = w + 16 * k;
        float val = -INFINITY;
        if (jv && i < 257) val = zb[(size_t)i * ZCOL + j] + ub[i];
        zz[k] = val; mx = fmaxf(mx, val);
    }
    red[w][lane] = mx;
    __syncthreads();
    float M = -INFINITY;
    #pragma unroll
    for (int ww = 0; ww < 16; ++ww) M = fmaxf(M, red[ww][lane]);
    __syncthreads();
    float s = 0.f;
    if (jv) {
        #pragma unroll
        for (int k = 0; k < 17; ++k) s += expf(zz[k] - M);
    }
    red[w][lane] = s;
    __syncthreads();
    if (w == 0 && jv) {
        float S = 0.f;
        #pragma unroll
        for (int ww = 0; ww < 16; ++ww) S += red[ww][lane];
        const float lnu = (j < 1024) ? NORM_C : (LOG_MS + NORM_C);
        v[b * ZCOL + j] = lnu - (M + logf(S));
    }
}

__global__ void sink_out_kernel(const float* __restrict__ Z0, const float* __restrict__ u,
                                const float* __restrict__ v, float* __restrict__ out)
{
    const int j = blockIdx.x * 256 + threadIdx.x;
    const int i = blockIdx.y, b = blockIdx.z;
    if (j < ZCOL) {
        const size_t idx = (size_t)b * ZBAT + (size_t)i * ZCOL + j;
        out[idx] = Z0[idx] + u[b * 257 + i] + v[b * ZCOL + j] + LOG_TOT;
    }
}

// ---------------------------------------------------------------------------
static inline void gemm(hipStream_t st, const float* W, const float* X0,
                        const float* X1, int C0, const float* bias,
                        const float* res, int Nr, float* out, int No,
                        int O, int C, int N, int relu)
{
    dim3 g(N / 128, O / 128);
    gemm_kernel<<<g, 256, 0, st>>>(W, X0, X1, bias, res, out, O, C, C0, N, Nr, No, relu);
}

extern "C" void kernel_launch(void* const* d_in, const int* in_sizes, int n_in,
                              void* d_out, int out_size, void* d_ws, size_t ws_size,
                              hipStream_t stream)
{
    (void)in_sizes; (void)n_in; (void)out_size; (void)ws_size;
    const float* det_in = (const float*)d_in[0];
    const float* trk_in = (const float*)d_in[1];
    const float* enc_w1 = (const float*)d_in[2];
    const float* enc_b1 = (const float*)d_in[3];
    const float* enc_w2 = (const float*)d_in[4];
    const float* enc_b2 = (const float*)d_in[5];
    const float* fus_pw = (const float*)d_in[6];
    const float* fus_pb = (const float*)d_in[7];
    const float* fus_mw = (const float*)d_in[8];
    const float* fus_mb = (const float*)d_in[9];
    const float* fus_m1w = (const float*)d_in[10];
    const float* fus_m1b = (const float*)d_in[11];
    const float* fus_m2w = (const float*)d_in[12];
    const float* fus_m2b = (const float*)d_in[13];
    const float* gnn_pw = (const float*)d_in[14];
    const float* gnn_pb = (const float*)d_in[15];
    const float* gnn_mw = (const float*)d_in[16];
    const float* gnn_mb = (const float*)d_in[17];
    const float* gnn_m1w = (const float*)d_in[18];
    const float* gnn_m1b = (const float*)d_in[19];
    const float* gnn_m2w = (const float*)d_in[20];
    const float* gnn_m2b = (const float*)d_in[21];
    const float* final_w = (const float*)d_in[22];
    const float* final_b = (const float*)d_in[23];
    const float* bin_sc  = (const float*)d_in[24];
    float* out = (float*)d_out;

    float* ws = (float*)d_ws;
    float* XF   = ws;                      // 4,194,304  fuser state x [256][16384]
    float* R    = ws + 4194304;            // 16,777,216 temp arena
    float* COMB = ws + 20971520;           // 1,310,720  [256][5120] tr|det state
    float* Z0   = ws + 22282240;           // 1,053,700
    float* U    = ws + 23335940;           //     1,028
    float* V    = ws + 23336968;           //     4,100
    // arena aliases (fuser / det-enc): Q,K,V contiguous so qkv is one O=768 GEMM
    float* Qf = R;
    float* Kf = R + 4194304;
    float* Vf = R + 8388608;
    float* MS = R + 12582912;
    // arena aliases (GNN, combined N=5120):
    float* QKV = R;                       // [768][5120] = 3,932,160
    float* H   = R + 1310720;             // [512][5120] overlays K,V rows
    float* MSG = R + 3932160;             // [256][5120]
    float* M   = R + 5242880;             // [256][5120]
    const float* Qt = QKV;
    const float* Kt = QKV + (size_t)256 * NCB;
    const float* Vt = QKV + (size_t)512 * NCB;
    const float* Qd = Qt + 1024;
    const float* Kd = Kt + 1024;
    const float* Vd = Vt + 1024;

    // ================= encoder (tracks) + fuser ===========================
    pe_kernel<<<NCT/256, 256, 0, stream>>>(trk_in, MS, NCT, 4, 257*16);
    repack_kernel<<<dim3(NCT/256, 256), 256, 0, stream>>>(trk_in, Qf, NCT, 4, 257*16);
    gemm(stream, enc_w1, Qf, Qf, 256, enc_b1, nullptr, 0, Kf, NCT, 256, 256, NCT, 1);
    gemm(stream, enc_w2, Kf, Kf, 256, enc_b2, MS, NCT, XF, NCT, 256, 256, NCT, 0);

    for (int l = 0; l < 4; ++l) {
        gemm(stream, fus_pw + l*196608, XF, XF, 256, fus_pb + l*768,
             nullptr, 0, Qf, NCT, 768, 256, NCT, 0);
        fuser_attn_kernel<<<1024, 256, 0, stream>>>(Qf, Kf, Vf, MS);
        gemm(stream, fus_mw + l*65536, MS, MS, 256, fus_mb + l*256,
             nullptr, 0, Qf, NCT, 256, 256, NCT, 0);               // M -> Qf
        gemm(stream, fus_m1w + l*262144, XF, Qf, 256, fus_m1b + l*512,
             nullptr, 0, Kf, NCT, 512, 512, NCT, 1);               // H -> Kf..Vf
        gemm(stream, fus_m2w + l*131072, Kf, Kf, 512, fus_m2b + l*256,
             XF, NCT, XF, NCT, 256, 512, NCT, 0);                  // x += ...
    }
    meanpool_kernel<<<dim3(4, 256), 256, 0, stream>>>(XF, COMB);   // tr cols [0,1024)

    // ================= encoder (detections) -> COMB cols [1024,5120) ======
    pe_kernel<<<NCD/256, 256, 0, stream>>>(det_in, MS, NCD, 10, 257*1024);
    repack_kernel<<<dim3(NCD/256, 256), 256, 0, stream>>>(det_in, Qf, NCD, 10, 257*1024);
    gemm(stream, enc_w1, Qf, Qf, 256, enc_b1, nullptr, 0, Kf, NCD, 256, 256, NCD, 1);
    gemm(stream, enc_w2, Kf, Kf, 256, enc_b2, MS, NCD, COMB + 1024, NCB, 256, 256, NCD, 0);

    // ================= GNN (combined tr|det, N=5120) ======================
    for (int l = 0; l < 12; ++l) {
        const float* pw  = gnn_pw + l*196608;
        const float* pb  = gnn_pb + l*768;
        const float* mw  = gnn_mw + l*65536;
        const float* mb  = gnn_mb + l*256;
        const float* m1w = gnn_m1w + l*262144;
        const float* m1b = gnn_m1b + l*512;
        const float* m2w = gnn_m2w + l*131072;
        const float* m2b = gnn_m2b + l*256;
        const bool cross = (l & 1);

        gemm(stream, pw, COMB, COMB, 256, pb, nullptr, 0, QKV, NCB, 768, 256, NCB, 0);

        attn_kernel<<<dim3(4, 4, 4), 256, 0, stream>>>(
            Qt, cross ? Kd : Kt, cross ? Vd : Vt, MSG,
            256, cross ? 1024 : 256, NCB, NCB);
        attn_kernel<<<dim3(16, 4, 4), 256, 0, stream>>>(
            Qd, cross ? Kt : Kd, cross ? Vt : Vd, MSG + 1024,
            1024, cross ? 256 : 1024, NCB, NCB);

        gemm(stream, mw, MSG, MSG, 256, mb, nullptr, 0, M, NCB, 256, 256, NCB, 0);
        gemm(stream, m1w, COMB, M, 256, m1b, nullptr, 0, H, NCB, 512, 512, NCB, 1);
        gemm(stream, m2w, H, H, 512, m2b, COMB, NCB, COMB, NCB, 256, 512, NCB, 0);
    }

    // ================= final projection + scores + sinkhorn ===============
    gemm(stream, final_w, COMB, COMB, 256, final_b, nullptr, 0, M, NCB, 256, 256, NCB, 0);
    scores_kernel<<<dim3(16, 4, 4), 256, 0, stream>>>(M, Z0);
    sink_init_kernel<<<21, 256, 0, stream>>>(Z0, V, bin_sc);
    for (int it = 0; it < 100; ++it) {
        sink_u_kernel<<<257, 256, 0, stream>>>(Z0, V, U);
        sink_v_kernel<<<dim3(17, 4), 1024, 0, stream>>>(Z0, U, V);
    }
    sink_out_kernel<<<dim3(5, 257, 4), 256, 0, stream>>>(Z0, U, V, out);
}